// Round 16
// baseline (592.471 us; speedup 1.0000x reference)
//
#include <hip/hip_runtime.h>

#define B_SZ 2048
#define HID  1024
#define G4   4096
#define IN_D 512
#define T_LEN 20
#define NT   (HID/32)

// Tile swizzle: 16B chunk q of row r stored at q ^ ((r>>1)&3) -> b128 frag
// reads land 8 banks x 2-way (free, m136); DMA writes stay linear.
#define POFF(r, q) ((r)*32 + ((((q) ^ (((r) >> 1) & 3))) << 3))

typedef __attribute__((ext_vector_type(8))) _Float16 f16x8;
typedef __attribute__((ext_vector_type(4))) float f32x4;
typedef const __attribute__((address_space(1))) void* gas_p;
typedef __attribute__((address_space(3))) void* las_p;

__device__ __forceinline__ float bf2f(ushort u){
  union { unsigned int i; float f; } v; v.i = ((unsigned int)u) << 16; return v.f;
}
__device__ __forceinline__ ushort f2bf(float f){
  union { float f; unsigned int i; } v; v.f = f;
  unsigned int r = v.i + 0x7fffu + ((v.i >> 16) & 1u);
  return (ushort)(r >> 16);
}
// fp16 RTN. All tensor magnitudes here (|h|<=1, |W|~0.03, |c0|~N(0,1)) are far
// inside fp16 range; rel err 2^-11 beats bf16's 2^-9.
__device__ __forceinline__ ushort f2h(float f){
  _Float16 h = (_Float16)f;
  union { _Float16 h; ushort u; } v; v.h = h; return v.u;
}
__device__ __forceinline__ float rdv(const void* p, long idx, int fl){
  return fl ? ((const float*)p)[idx] : bf2f(((const ushort*)p)[idx]);
}
__device__ __forceinline__ float sigm(float x){ return 1.0f/(1.0f + __expf(-x)); }
__device__ __forceinline__ float tanh_f(float x){
  float e = __expf(2.0f*x);
  return 1.0f - 2.0f/(e + 1.0f);
}

// flag=1 -> fp32 inputs; flag=0 -> bf16.
__global__ void detect_dtype(const ushort* __restrict__ h0bits, int* __restrict__ flag){
  int weird = 0;
  for (int i = 0; i < 256; i += 2){
    float a = fabsf(bf2f(h0bits[i]));
    if (!(a >= 1e-8f && a <= 1e4f)) weird++;
  }
  *flag = (weird >= 32) ? 1 : 0;
}

// Packed+swizzled fp16 layouts (every wave-level access = dense span):
//   h: tile (mb*32+kt) of 4096 halfs, element (b&127, j&31) at POFF
//   W: tile (nb*32+kt) of 4096 halfs, row r = g*32+(j&31)
__global__ void canon(const void* __restrict__ h0, const void* __restrict__ c0,
                      const void* __restrict__ whh, const int* __restrict__ flag,
                      ushort* __restrict__ hA,
                      float* __restrict__ c_state,
                      ushort* __restrict__ wpk){
  const int fl = *flag;
  long i = (long)blockIdx.x * 256 + threadIdx.x;
  const long N1 = (long)B_SZ * HID;
  const long N3 = (long)G4 * HID;
  if (i < N1){
    const int b = (int)(i >> 10), j = (int)(i & 1023);
    const int r = b & 127, q = (j >> 3) & 3;
    const long po = ((long)(b >> 7)*32 + (j >> 5))*4096 + POFF(r, q) + (j & 7);
    hA[po] = f2h(rdv(h0, i, fl));
    return;
  }
  i -= N1;
  if (i < N1){ c_state[i] = rdv(c0, i, fl); return; }
  i -= N1;
  if (i < N3){
    const int n = (int)(i >> 10), k = (int)(i & 1023);
    const int g = n >> 10, j = n & 1023;
    const int nb = j >> 5, r = g*32 + (j & 31);
    const int kt = k >> 5, q = (k >> 3) & 3;
    const long base = ((long)(nb*32 + kt))*4096 + POFF(r, q) + (k & 7);
    wpk[base] = f2h(rdv(whh, i, fl));
  }
}

// Fold embedding + input GEMM + biases into exact rank-2 update:
// gates_x[t,b,n] = obs[t,b,0]*M0[n] + obs[t,b,1]*M1[n] + Beff[n]
__global__ void fold_emb(const void* __restrict__ Wih, const void* __restrict__ Wemb,
                         const void* __restrict__ bemb, const void* __restrict__ bih,
                         const void* __restrict__ bhh, const int* __restrict__ flag,
                         float* __restrict__ M0, float* __restrict__ M1, float* __restrict__ Beff){
  const int n = blockIdx.x;
  const int lane = threadIdx.x;
  const int fl = *flag;
  float s0 = 0.f, s1 = 0.f, sb = 0.f;
  for (int j = lane; j < IN_D; j += 64){
    float w  = rdv(Wih, (long)n*IN_D + j, fl);
    float e0 = rdv(Wemb, 2L*j, fl);
    float e1 = rdv(Wemb, 2L*j + 1, fl);
    float be = rdv(bemb, j, fl);
    s0 += w*e0; s1 += w*e1; sb += w*be;
  }
  #pragma unroll
  for (int off = 32; off > 0; off >>= 1){
    s0 += __shfl_down(s0, off, 64);
    s1 += __shfl_down(s1, off, 64);
    sb += __shfl_down(sb, off, 64);
  }
  if (lane == 0){
    M0[n] = s0; M1[n] = s1;
    Beff[n] = sb + rdv(bih, n, fl) + rdv(bhh, n, fl);
  }
}

// R15 (585us best) with prefetch depth 3 -> 4: 5-buffer ring (80 KB LDS),
// vmcnt(6) steady state (tiles kt+1..kt+4 in flight; wait frees only kt+1's
// 2 loads). The depth curve is the session's strongest measured slope
// (depth 1->2: -14us, 2->3: -50us); this is the last rung -- 2 blocks x 80KB
// = 160KB = the CU's entire LDS pool. Ring ledger: DMA target (cur+4)%5 =
// tile kt-1's buffer, freed at kt-1's barrier; tile kt+1 residency fenced by
// own vmcnt(6)+s_barrier; tail ladder 4->2->0. Numerics/layout/epilogue
// identical to R15 -> bit-identical output.
__global__ __launch_bounds__(512, 4)
void lstm_step(const ushort* __restrict__ hin, ushort* __restrict__ hout,
               void* __restrict__ out_final,
               float* __restrict__ c_state,
               const ushort* __restrict__ wpk,
               const float* __restrict__ M0, const float* __restrict__ M1,
               const float* __restrict__ Beff,
               const void* __restrict__ obs_raw, int t_step,
               const int* __restrict__ flag, int is_final)
{
  // 5-ring x [A 4096 | B 4096] halfs = 80 KB
  __shared__ __align__(16) ushort lds[5*8192];

  const int tid  = threadIdx.x;
  const int wave = tid >> 6;
  const int lane = tid & 63;
  const int l15  = lane & 15;
  const int quad = lane >> 4;
  const int wm   = wave & 3;    // M quarter (32 rows)
  const int wn   = wave >> 2;   // j half (16 cols of each gate)

  // XCD partition: xcd x owns mb in {(x&1)*8 + 0..7}, nb in {(x>>1)*8 + 0..7}
  // -> per-XCD L2 working set = A 2MB + W 2MB (R4-proven: FETCH stays ideal).
  const int bid = blockIdx.x;
  const int xcd = bid & 7, u = bid >> 3;
  const int mb  = ((xcd & 1) << 3) | (u & 7);       // 0..15
  const int nb  = ((xcd >> 1) << 3) | (u >> 3);     // 0..31
  const int n0  = nb << 5;

  f32x4 acc[4][2];   // [gate][mt]
  #pragma unroll
  for (int g = 0; g < 4; g++)
    #pragma unroll
    for (int mt = 0; mt < 2; mt++)
      acc[g][mt] = (f32x4){0.f, 0.f, 0.f, 0.f};

  const ushort* aB = hin + (size_t)mb*32*4096;
  const ushort* wB = wpk + (size_t)nb*32*4096;

  const int dOff = tid*8;   // halfs; 512 thr x 16B = full 8KB tile per instr

  // 2 vmcnt-counted instructions per tile stage (the vmcnt math relies on this).
  #define DMA_TILE(kt, buf) do {                                              \
    const ushort* s0 = aB + (size_t)(kt)*4096;                                \
    const ushort* s1 = wB + (size_t)(kt)*4096;                                \
    ushort* d = &lds[(buf)*8192];                                             \
    __builtin_amdgcn_global_load_lds((gas_p)(s0+dOff), (las_p)(d+dOff),      16,0,0); \
    __builtin_amdgcn_global_load_lds((gas_p)(s1+dOff), (las_p)(d+4096+dOff), 16,0,0); \
  } while (0)

  // kt-invariant swizzled frag-read offsets (halfs)
  int offA[2], offB[4];
  #pragma unroll
  for (int mt = 0; mt < 2; mt++) {
    const int r = wm*32 + mt*16 + l15;             // 0..127
    offA[mt] = POFF(r, quad);
  }
  #pragma unroll
  for (int g = 0; g < 4; g++) {
    const int r = g*32 + wn*16 + l15;              // 0..127
    offB[g] = 4096 + POFF(r, quad);
  }

  // Prologue: stage tiles 0..3; wait only tile 0's loads (6 stay in flight).
  DMA_TILE(0, 0);
  DMA_TILE(1, 1);
  DMA_TILE(2, 2);
  DMA_TILE(3, 3);
  asm volatile("s_waitcnt vmcnt(6)" ::: "memory");
  asm volatile("s_barrier" ::: "memory");

  int cur = 0;
  #pragma unroll 1
  for (int kt = 0; kt < NT; kt++) {
    const int sb = cur * 8192;

    f16x8 a[2], b[4];
    #pragma unroll
    for (int mt = 0; mt < 2; mt++)
      a[mt] = *reinterpret_cast<const f16x8*>(&lds[sb + offA[mt]]);
    #pragma unroll
    for (int g = 0; g < 4; g++)
      b[g] = *reinterpret_cast<const f16x8*>(&lds[sb + offB[g]]);

    // Issue tile kt+4 now: needed 4 barriers from now; its L2 latency hides
    // under this iter's MFMAs and the next three iters' work.
    if (kt + 4 < NT) {
      int stg = cur + 4; if (stg >= 5) stg -= 5;
      DMA_TILE(kt + 4, stg);
    }

    #pragma unroll
    for (int g = 0; g < 4; g++) {
      acc[g][0] = __builtin_amdgcn_mfma_f32_16x16x32_f16(a[0], b[g], acc[g][0], 0, 0, 0);
      acc[g][1] = __builtin_amdgcn_mfma_f32_16x16x32_f16(a[1], b[g], acc[g][1], 0, 0, 0);
    }

    // Counted wait: free only tile kt+1's 2 loads; deeper tiles stay in
    // flight across the barrier (no full drain until the tail).
    if      (kt + 4 < NT) asm volatile("s_waitcnt vmcnt(6)" ::: "memory");
    else if (kt + 3 < NT) asm volatile("s_waitcnt vmcnt(4)" ::: "memory");
    else if (kt + 2 < NT) asm volatile("s_waitcnt vmcnt(2)" ::: "memory");
    else                  asm volatile("s_waitcnt vmcnt(0)" ::: "memory");
    asm volatile("s_barrier" ::: "memory");
    __builtin_amdgcn_sched_barrier(0);

    cur = (cur == 4) ? 0 : cur + 1;
  }
  #undef DMA_TILE

  // Epilogue: fused LSTM cell. C/D layout: col = lane&15, row = quad*4 + reg.
  const int fl = *flag;
  const int j = n0 + wn*16 + l15;
  float bi[4], m0v[4], m1v[4];
  #pragma unroll
  for (int g = 0; g < 4; g++) {
    bi[g]  = Beff[g*HID + j];
    m0v[g] = M0[g*HID + j];
    m1v[g] = M1[g*HID + j];
  }
  const int jq = (j >> 3) & 3;   // k-chunk of col j in next step's packed h
  #pragma unroll
  for (int mt = 0; mt < 2; mt++) {
    #pragma unroll
    for (int r = 0; r < 4; r++) {
      const int bl7 = wm*32 + mt*16 + quad*4 + r;   // b & 127
      const int b   = mb*128 + bl7;
      const long oidx = ((long)t_step * B_SZ + b) * 2;
      const float o0 = rdv(obs_raw, oidx, fl);
      const float o1 = rdv(obs_raw, oidx + 1, fl);
      const size_t off = (size_t)b*HID + j;
      float pi = acc[0][mt][r] + o0*m0v[0] + o1*m1v[0] + bi[0];
      float pf = acc[1][mt][r] + o0*m0v[1] + o1*m1v[1] + bi[1];
      float pg = acc[2][mt][r] + o0*m0v[2] + o1*m1v[2] + bi[2];
      float po = acc[3][mt][r] + o0*m0v[3] + o1*m1v[3] + bi[3];
      float cn = sigm(pf)*c_state[off] + sigm(pi)*tanh_f(pg);
      float hn = sigm(po)*tanh_f(cn);
      c_state[off] = cn;
      if (is_final) {
        if (fl) ((float*)out_final)[off] = hn;
        else    ((ushort*)out_final)[off] = f2bf(hn);
      } else {
        const long hpo = ((long)mb*32 + (j >> 5))*4096 + POFF(bl7, jq) + (j & 7);
        hout[hpo] = f2h(hn);
      }
    }
  }
}

extern "C" void kernel_launch(void* const* d_in, const int* in_sizes, int n_in,
                              void* d_out, int out_size, void* d_ws, size_t ws_size,
                              hipStream_t stream) {
  const void* obs  = d_in[0];
  const void* h0   = d_in[1];
  const void* c0   = d_in[2];
  const void* Wemb = d_in[3];
  const void* bemb = d_in[4];
  const void* Wih  = d_in[5];
  const void* Whh  = d_in[6];
  const void* bih  = d_in[7];
  const void* bhh  = d_in[8];

  char* w = (char*)d_ws;
  int*    flag    = (int*)w;
  float*  M0      = (float*)(w + 256);
  float*  M1      = M0 + G4;
  float*  Beff    = M1 + G4;
  float*  c_state = Beff + G4;                              // 8 MB
  ushort* wpk     = (ushort*)(c_state + (size_t)B_SZ*HID);  // 8 MB packed W (fp16)
  ushort* hA      = wpk + (size_t)G4*HID;                   // 4 MB
  ushort* hB      = hA + (size_t)B_SZ*HID;                  // 4 MB  (~24 MB total)

  detect_dtype<<<1, 1, 0, stream>>>((const ushort*)h0, flag);

  long totalCanon = 2L*B_SZ*HID + (long)G4*HID;
  canon<<<(int)((totalCanon + 255)/256), 256, 0, stream>>>(
      h0, c0, Whh, flag, hA, c_state, wpk);

  fold_emb<<<G4, 64, 0, stream>>>(Wih, Wemb, bemb, bih, bhh, flag, M0, M1, Beff);

  for (int t = 0; t < T_LEN; t++) {
    const ushort* ih = (t & 1) ? hB : hA;
    ushort* oh = (t & 1) ? hA : hB;
    lstm_step<<<512, 512, 0, stream>>>(ih, oh, d_out, c_state,
                                       wpk, M0, M1, Beff,
                                       obs, t, flag, (t == T_LEN - 1) ? 1 : 0);
  }
}